// Round 7
// baseline (260.947 us; speedup 1.0000x reference)
//
#include <hip/hip_runtime.h>
#include <cstdint>

// GraphormerMultiHeadAttention on MI355X (gfx950), bf16 MFMA path.
// B=16, N=512, D=1024, H=16, hd=64. scale = D^-0.5 = 1/32.
//
// R8 -> R9:
//  - attn restored to the R6 config (best "total - qkv" across sessions, even
//    clock-handicapped): QBLK=64, 256 threads, direct Q->reg (no sQ), 25.6KB
//    LDS, launch_bounds(256,5) -> 5 blocks/CU. QBLK=128 (R8) halved staging
//    traffic but cost block-level TLP (2x512t vs 5x256t) - net null/worse.
//  - softmax scaling folded OUT of the attn inner loop: Q pre-scaled by
//    log2(e)/32 in the qkv epilogue (Q feeds only attn), bias pre-scaled by
//    log2(e) in bias_perm; attn computes ev = exp2(s + bias): v_add + native
//    v_exp_f32 instead of fma+mul+exp (~134M VALU ops removed).
//  - qkv/oproj/casts unchanged (qkv at structural ceiling: 70us = 51.5GF/740TF,
//    FETCH/WRITE at ideal 49.2MB, 0 bank conflicts).

typedef unsigned short u16;
typedef unsigned int   u32;
typedef __attribute__((ext_vector_type(8))) short bf8;   // 8 x bf16 (4 VGPRs)
typedef __attribute__((ext_vector_type(4))) float f4;    // 4 x f32 accum

#define LOG2E 1.4426950408889634f

__device__ __forceinline__ u16 f2bf(float x) {
  u32 u = __float_as_uint(x);
  u += 0x7FFF + ((u >> 16) & 1);        // round-to-nearest-even
  return (u16)(u >> 16);
}

__device__ __forceinline__ float bf2f(u16 x) {
  return __uint_as_float(((u32)x) << 16);
}

// async global->LDS, 16B per lane. LDS dest = wave-uniform base + lane*16.
__device__ __forceinline__ void gl2lds16(const void* g, void* l) {
  __builtin_amdgcn_global_load_lds(
      (const __attribute__((address_space(1))) u32*)g,
      (__attribute__((address_space(3))) u32*)l, 16, 0, 0);
}

// ---------------- cast kernels ----------------

__global__ __launch_bounds__(256) void cast_bf16(const float* __restrict__ src,
                                                 uint4* __restrict__ dst, int n8) {
  const int i = blockIdx.x * 256 + threadIdx.x;
  if (i >= n8) return;
  const float4* s = (const float4*)src;
  const float4 a = s[2 * i], c = s[2 * i + 1];
  uint4 o;
  o.x = (u32)f2bf(a.x) | ((u32)f2bf(a.y) << 16);
  o.y = (u32)f2bf(a.z) | ((u32)f2bf(a.w) << 16);
  o.z = (u32)f2bf(c.x) | ((u32)f2bf(c.y) << 16);
  o.w = (u32)f2bf(c.z) | ((u32)f2bf(c.w) << 16);
  dst[i] = o;
}

// 4 weight matrices (1M elems each) in one launch: i>>17 selects the matrix.
__global__ __launch_bounds__(256) void cast4_bf16(
    const float* __restrict__ s0, const float* __restrict__ s1,
    const float* __restrict__ s2, const float* __restrict__ s3,
    uint4* __restrict__ d0, uint4* __restrict__ d1,
    uint4* __restrict__ d2, uint4* __restrict__ d3) {
  const int i = blockIdx.x * 256 + threadIdx.x;     // 0 .. 524287
  const int w = i >> 17, j = i & 131071;
  const float* src = (w == 0) ? s0 : (w == 1) ? s1 : (w == 2) ? s2 : s3;
  uint4* dst = (w == 0) ? d0 : (w == 1) ? d1 : (w == 2) ? d2 : d3;
  const float4* s = (const float4*)src;
  const float4 a = s[2 * j], c = s[2 * j + 1];
  uint4 o;
  o.x = (u32)f2bf(a.x) | ((u32)f2bf(a.y) << 16);
  o.y = (u32)f2bf(a.z) | ((u32)f2bf(a.w) << 16);
  o.z = (u32)f2bf(c.x) | ((u32)f2bf(c.y) << 16);
  o.w = (u32)f2bf(c.z) | ((u32)f2bf(c.w) << 16);
  dst[j] = o;
}

// bias = bf16((sp+ed)*log2e), permuted so attn lane `tid` of block (b, qt, jt)
// reads its 16 values (4 rows x 4 col-groups) as one contiguous 32B chunk.
__global__ __launch_bounds__(256) void bias_perm(const float* __restrict__ sp,
                                                 const float* __restrict__ ed,
                                                 u16* __restrict__ Bp) {
  const int jt = blockIdx.x, qt = blockIdx.y, b = blockIdx.z;
  const int tid = threadIdx.x;
  const int wave = tid >> 6, quad = (tid >> 4) & 3, l16 = tid & 15;
  const int qrl = (wave << 4) + (quad << 2);
  union { u16 a[16]; uint4 v[2]; } tmp;
#pragma unroll
  for (int nb = 0; nb < 4; nb++) {
    const int col = (jt << 6) + (nb << 4) + l16;
#pragma unroll
    for (int r = 0; r < 4; r++) {
      const int row = (qt << 6) + qrl + r;
      const size_t idx = ((size_t)b << 18) + (size_t)row * 512 + col;
      tmp.a[nb * 4 + r] = f2bf((sp[idx] + ed[idx]) * LOG2E);
    }
  }
  uint4* out = (uint4*)Bp + ((((size_t)b * 8 + qt) * 8 + jt) * 256 + tid) * 2;
  out[0] = tmp.v[0];
  out[1] = tmp.v[1];
}

// ---------------- GEMM core: C(128x128) = A(128x1024) * Bt(128x1024)^T ----------------
// A row-major [M][1024], Bt row-major [Nout][1024] (computes A @ Bt^T).
// LDS tiles are [128 rows][8 chunks of 16B], slot (r,c) holds global chunk c^(r&7).
// SWAP=true computes C^T fragments (mfma(B,A)): lane&15 -> M dim, (quad,reg) -> N
// dim, so the 4 regs of each fragment are CONSECUTIVE along N -> packed stores.

template <bool SWAP>
__device__ __forceinline__ void gemm_core(const u16* __restrict__ A,
                                          const u16* __restrict__ Bt,
                                          int m0, int n0,
                                          u16* lA, u16* lB, f4 acc[4][4]) {
  const int tid  = threadIdx.x;
  const int wave = tid >> 6;
  const int lane = tid & 63;
  const int quad = lane >> 4;
  const int l16  = lane & 15;
  const int wm   = (wave >> 1) << 6;
  const int wn   = (wave & 1) << 6;
  const int srow = tid >> 3;
  const int scol = ((tid & 7) ^ (srow & 7)) << 3;   // swizzled source chunk
  const int c0   = (quad ^ (l16 & 7)) << 3;         // swizzled read offset, kk=0

  f4 zero = {0.f, 0.f, 0.f, 0.f};
#pragma unroll
  for (int mi = 0; mi < 4; mi++)
#pragma unroll
    for (int ni = 0; ni < 4; ni++) acc[mi][ni] = zero;

  const u16* Ab = A  + (size_t)(m0 + srow) * 1024 + scol;
  const u16* Bb = Bt + (size_t)(n0 + srow) * 1024 + scol;

  for (int k0 = 0; k0 < 1024; k0 += 64) {
    __syncthreads();   // protect LDS from previous iteration's readers
#pragma unroll
    for (int i = 0; i < 4; i++) {
      gl2lds16(Ab + (size_t)(i << 5) * 1024 + k0,
               (char*)lA + (((i << 8) + (wave << 6)) << 4));
      gl2lds16(Bb + (size_t)(i << 5) * 1024 + k0,
               (char*)lB + (((i << 8) + (wave << 6)) << 4));
    }
    __syncthreads();   // drains vmcnt(0) -> tiles visible
#pragma unroll
    for (int kk = 0; kk < 64; kk += 32) {
      const int o = c0 ^ kk;
      bf8 af[4], bfr[4];
#pragma unroll
      for (int mi = 0; mi < 4; mi++)
        af[mi] = *(const bf8*)(lA + (wm + (mi << 4) + l16) * 64 + o);
#pragma unroll
      for (int ni = 0; ni < 4; ni++)
        bfr[ni] = *(const bf8*)(lB + (wn + (ni << 4) + l16) * 64 + o);
#pragma unroll
      for (int mi = 0; mi < 4; mi++)
#pragma unroll
        for (int ni = 0; ni < 4; ni++) {
          if (SWAP)
            acc[mi][ni] = __builtin_amdgcn_mfma_f32_16x16x32_bf16(
                bfr[ni], af[mi], acc[mi][ni], 0, 0, 0);
          else
            acc[mi][ni] = __builtin_amdgcn_mfma_f32_16x16x32_bf16(
                af[mi], bfr[ni], acc[mi][ni], 0, 0, 0);
        }
    }
  }
}

// ---------------- QKV projection ----------------
// XCD remap: flat bits [2:0]=m_lo [5:3]=n_tile [8:6]=m_hi [10:9]=proj.
// Q is pre-scaled by log2e/32 (softmax scale folded in; Q feeds only attn).

__global__ __launch_bounds__(256) void qkv_kernel(
    const u16* __restrict__ xb, const u16* __restrict__ wq,
    const u16* __restrict__ wk, const u16* __restrict__ wv,
    u16* __restrict__ Qh, u16* __restrict__ Kh, u16* __restrict__ Vt) {
  __shared__ __align__(16) u16 lA[128 * 64];
  __shared__ __align__(16) u16 lB[128 * 64];
  const int flat = blockIdx.x + (blockIdx.y << 3) + (blockIdx.z << 9);
  const int m_tile = (flat & 7) | (((flat >> 6) & 7) << 3);
  const int n_tile = (flat >> 3) & 7;
  const int proj = flat >> 9;
  const int m0 = m_tile << 7, n0 = n_tile << 7;
  const u16* W = (proj == 0) ? wq : (proj == 1) ? wk : wv;

  const int tid = threadIdx.x, wave = tid >> 6, lane = tid & 63;
  const int quad = lane >> 4, l16 = lane & 15;
  const int wm = (wave >> 1) << 6, wn = (wave & 1) << 6;
  f4 acc[4][4];

  if (proj == 2) {
    // V: normal orientation; C rows (quad,reg) = tokens, which are the
    // contiguous dim of Vt [B,H,hd,512] -> ushort4 over 4 consecutive n.
    gemm_core<false>(xb, W, m0, n0, lA, lB, acc);
#pragma unroll
    for (int mi = 0; mi < 4; mi++) {
      const int gmb = m0 + wm + (mi << 4) + (quad << 2);
      const int b = gmb >> 9, nb = gmb & 511;
#pragma unroll
      for (int ni = 0; ni < 4; ni++) {
        const int gn = n0 + wn + (ni << 4) + l16;
        const int h = gn >> 6, hdi = gn & 63;
        ushort4 pk;
        pk.x = f2bf(acc[mi][ni][0]);
        pk.y = f2bf(acc[mi][ni][1]);
        pk.z = f2bf(acc[mi][ni][2]);
        pk.w = f2bf(acc[mi][ni][3]);
        *(ushort4*)(Vt + ((size_t)((b << 4) + h) * 64 + hdi) * 512 + nb) = pk;
      }
    }
  } else {
    // Q/K: transposed fragments; (quad,reg) = hd (contiguous in Qh/Kh),
    // lane&15 = token row -> one ushort4 per fragment.
    gemm_core<true>(xb, W, m0, n0, lA, lB, acc);
    u16* dst = (proj == 0) ? Qh : Kh;
    const float qs = (proj == 0) ? (LOG2E / 32.0f) : 1.0f;
#pragma unroll
    for (int mi = 0; mi < 4; mi++) {
      const int gm = m0 + wm + (mi << 4) + l16;      // token row
      const int b = gm >> 9, n = gm & 511;
#pragma unroll
      for (int ni = 0; ni < 4; ni++) {
        const int gn = n0 + wn + (ni << 4) + (quad << 2);  // hd dim
        const int h = gn >> 6, hdi = gn & 63;
        ushort4 pk;
        pk.x = f2bf(acc[mi][ni][0] * qs);
        pk.y = f2bf(acc[mi][ni][1] * qs);
        pk.z = f2bf(acc[mi][ni][2] * qs);
        pk.w = f2bf(acc[mi][ni][3] * qs);
        *(ushort4*)(dst + ((size_t)((b << 4) + h) * 512 + n) * 64 + hdi) = pk;
      }
    }
  }
}

// ---------------- output projection ----------------
// XCD remap: flat bits [2:0]=m_lo [5:3]=n_tile [8:6]=m_hi.
// Transposed fragments -> float4 stores (gn contiguous).

__global__ __launch_bounds__(256) void oproj_kernel(const u16* __restrict__ Ob,
                                                    const u16* __restrict__ wo,
                                                    float* __restrict__ out) {
  __shared__ __align__(16) u16 lA[128 * 64];
  __shared__ __align__(16) u16 lB[128 * 64];
  const int flat = blockIdx.x + (blockIdx.y << 3);
  const int m0 = ((flat & 7) | (((flat >> 6) & 7) << 3)) << 7;
  const int n0 = ((flat >> 3) & 7) << 7;
  f4 acc[4][4];
  gemm_core<true>(Ob, wo, m0, n0, lA, lB, acc);

  const int tid = threadIdx.x, wave = tid >> 6, lane = tid & 63;
  const int quad = lane >> 4, l16 = lane & 15;
  const int wm = (wave >> 1) << 6, wn = (wave & 1) << 6;
#pragma unroll
  for (int mi = 0; mi < 4; mi++) {
    const int gm = m0 + wm + (mi << 4) + l16;
#pragma unroll
    for (int ni = 0; ni < 4; ni++) {
      const int gn = n0 + wn + (ni << 4) + (quad << 2);
      float4 f;
      f.x = acc[mi][ni][0];
      f.y = acc[mi][ni][1];
      f.z = acc[mi][ni][2];
      f.w = acc[mi][ni][3];
      *(float4*)(out + (size_t)gm * 1024 + gn) = f;
    }
  }
}

// ---------------- fused attention: one wg per (64 q-rows, h, b) ----------------
// Q,K: [B,H,512,64] bf16 (Q pre-scaled by log2e/32).  Vt: [B,H,64,512] bf16.
// R3-proven stage-drain skeleton: per j-tile { bias loads; sync; stage K,V
// (4 gl2lds); sync (vmcnt0 drain); QK^T+softmax->sP; PV }.
// Q fragments loaded DIRECTLY global->register before the loop (contiguous 16B
// chunks, L2-hot): no sQ buffer. LDS = 25600 B; launch_bounds(256,5).
// Softmax: ev = exp2(s + bias) -- scale+log2e folded upstream; no max-sub
// (logits bounded); one sum reduce at end.

__global__ __launch_bounds__(256, 5) void attn_kernel(
    const u16* __restrict__ Qh, const u16* __restrict__ Kh,
    const u16* __restrict__ Vt, const u16* __restrict__ Bp,
    u16* __restrict__ Ob) {
  __shared__ __align__(16) u16 sK[64 * 64];
  __shared__ __align__(16) u16 sV[64 * 64];        // [hd][j] layout
  __shared__ __align__(16) u16 sP[4 * 16 * 72];    // stride 72 (pad vs bank conflicts)
  const int flat = blockIdx.x + (blockIdx.y << 3) + (blockIdx.z << 7);
  const int qt = (flat >> 3) & 7;
  const int h  = (flat >> 6) & 15;
  const int b  = (flat & 7) | (((flat >> 10) & 1) << 3);
  const int q0 = qt << 6;
  const int tid = threadIdx.x, wave = tid >> 6, lane = tid & 63;
  const int quad = lane >> 4, l16 = lane & 15;
  const int c0  = (quad ^ (l16 & 7)) << 3;                 // swizzled read offset
  const int swb = (((tid & 7) ^ ((tid >> 3) & 7)) << 4);   // swizzled staging byte off

  const u16* Qg = Qh + ((size_t)((b << 4) + h) * 512 + q0) * 64;
  const u16* Kg = Kh + (size_t)((b << 4) + h) * 512 * 64;
  const u16* Vg = Vt + (size_t)((b << 4) + h) * 64 * 512;
  const uint4* Bpg = (const uint4*)Bp + (((size_t)b * 8 + qt) * 8 * 256 + tid) * 2;

  // Q fragments direct from global: lane (wave,quad,l16) needs
  // Q[row=wave*16+l16][d = quad*8 .. +7] and the d+32 chunk — contiguous 16B.
  const bf8 aq0 = *(const bf8*)(Qg + ((wave << 4) + l16) * 64 + (quad << 3));
  const bf8 aq1 = *(const bf8*)(Qg + ((wave << 4) + l16) * 64 + 32 + (quad << 3));

  f4 o[4];
  f4 zero = {0.f, 0.f, 0.f, 0.f};
#pragma unroll
  for (int i = 0; i < 4; i++) o[i] = zero;
  float lsum[4] = {0.f, 0.f, 0.f, 0.f};
  const int qrl = (wave << 4) + (quad << 2);

  for (int j0 = 0; j0 < 512; j0 += 64) {
    // bias chunk for this j-tile: 32B/lane, issued before the drain barrier
    const uint4 bc0 = Bpg[(j0 >> 6) * 512];
    const uint4 bc1 = Bpg[(j0 >> 6) * 512 + 1];
    const u32 bw[8] = {bc0.x, bc0.y, bc0.z, bc0.w, bc1.x, bc1.y, bc1.z, bc1.w};

    __syncthreads();   // protect LDS from previous iteration's readers
#pragma unroll
    for (int i = 0; i < 2; i++) {
      const int e = (i << 8) + tid;
      gl2lds16((const char*)Kg + (size_t)j0 * 128 + (e >> 3) * 128 + swb,
               (char*)sK + (((i << 8) + (wave << 6)) << 4));
      gl2lds16((const char*)Vg + (size_t)(e >> 3) * 1024 + j0 * 2 + swb,
               (char*)sV + (((i << 8) + (wave << 6)) << 4));
    }
    __syncthreads();   // drains vmcnt(0) -> K/V tiles visible

    u16* pw = sP + wave * (16 * 72);
#pragma unroll
    for (int nb = 0; nb < 4; nb++) {
      bf8 b0 = *(const bf8*)(sK + ((nb << 4) + l16) * 64 + c0);
      bf8 b1 = *(const bf8*)(sK + ((nb << 4) + l16) * 64 + (c0 ^ 32));
      f4 s = zero;
      s = __builtin_amdgcn_mfma_f32_16x16x32_bf16(aq0, b0, s, 0, 0, 0);
      s = __builtin_amdgcn_mfma_f32_16x16x32_bf16(aq1, b1, s, 0, 0, 0);
#pragma unroll
      for (int r = 0; r < 4; r++) {
        const u32 w = bw[nb * 2 + (r >> 1)];
        const float bias = bf2f((r & 1) ? (u16)(w >> 16) : (u16)(w & 0xFFFF));
        const float ev = exp2f(s[r] + bias);     // scale+log2e pre-folded
        lsum[r] += ev;
        pw[((quad << 2) + r) * 72 + (nb << 4) + l16] = f2bf(ev);
      }
    }

    // P: C-layout -> LDS (per-wave region, in-wave ordering only)
    bf8 ap0 = *(const bf8*)(pw + l16 * 72 + (quad << 3));
    bf8 ap1 = *(const bf8*)(pw + l16 * 72 + 32 + (quad << 3));
#pragma unroll
    for (int db = 0; db < 4; db++) {
      bf8 v0 = *(const bf8*)(sV + ((db << 4) + l16) * 64 + c0);
      bf8 v1 = *(const bf8*)(sV + ((db << 4) + l16) * 64 + (c0 ^ 32));
      o[db] = __builtin_amdgcn_mfma_f32_16x16x32_bf16(ap0, v0, o[db], 0, 0, 0);
      o[db] = __builtin_amdgcn_mfma_f32_16x16x32_bf16(ap1, v1, o[db], 0, 0, 0);
    }
  }

  // epilogue: reduce row sums over the 16 l16-lanes, normalize, store
#pragma unroll
  for (int r = 0; r < 4; r++) {
    float s = lsum[r];
    s += __shfl_xor(s, 1);
    s += __shfl_xor(s, 2);
    s += __shfl_xor(s, 4);
    s += __shfl_xor(s, 8);
    const float inv = 1.f / s;
    const int gr = q0 + qrl + r;
#pragma unroll
    for (int db = 0; db < 4; db++)
      Ob[(size_t)((b << 9) + gr) * 1024 + (h << 6) + (db << 4) + l16] =
          f2bf(o[db][r] * inv);
  }
}

// ---------------- launch ----------------

extern "C" void kernel_launch(void* const* d_in, const int* in_sizes, int n_in,
                              void* d_out, int out_size, void* d_ws, size_t ws_size,
                              hipStream_t stream) {
  const float* x  = (const float*)d_in[0];
  const float* sp = (const float*)d_in[1];
  const float* ed = (const float*)d_in[2];
  const float* Wq = (const float*)d_in[3];
  const float* Wk = (const float*)d_in[4];
  const float* Wv = (const float*)d_in[5];
  const float* Wo = (const float*)d_in[6];
  float* out = (float*)d_out;

  char* w = (char*)d_ws;
  u16* xb  = (u16*)(w);                  // 16 MB  : x bf16 [8192][1024]
  u16* wqb = (u16*)(w + 16777216);       // 2 MB
  u16* wkb = (u16*)(w + 18874368);
  u16* wvb = (u16*)(w + 20971520);
  u16* wob = (u16*)(w + 23068672);
  u16* Qh  = (u16*)(w + 25165824);       // 16 MB  : [B,H,512,64] (pre-scaled)
  u16* Kh  = (u16*)(w + 41943040);       // 16 MB
  u16* Vt  = (u16*)(w + 58720256);       // 16 MB  : [B,H,64,512]
  u16* Ob  = (u16*)(w + 75497472);       // 16 MB  : [8192][1024]
  u16* Bp  = (u16*)(w + 92274688);       // 8 MB   : permuted bf16((sp+ed)*log2e)

  cast_bf16<<<4096, 256, 0, stream>>>(x, (uint4*)xb, 1048576);
  cast4_bf16<<<2048, 256, 0, stream>>>(Wq, Wk, Wv, Wo,
                                       (uint4*)wqb, (uint4*)wkb,
                                       (uint4*)wvb, (uint4*)wob);
  bias_perm<<<dim3(8, 8, 16), 256, 0, stream>>>(sp, ed, Bp);

  qkv_kernel<<<dim3(8, 64, 3), 256, 0, stream>>>(xb, wqb, wkb, wvb, Qh, Kh, Vt);
  attn_kernel<<<dim3(8, 16, 16), 256, 0, stream>>>(Qh, Kh, Vt, Bp, Ob);
  oproj_kernel<<<dim3(8, 64, 1), 256, 0, stream>>>(Ob, wob, out);
}

// Round 8
// 253.653 us; speedup vs baseline: 1.0288x; 1.0288x over previous
//
#include <hip/hip_runtime.h>
#include <cstdint>

// GraphormerMultiHeadAttention on MI355X (gfx950), bf16 MFMA path.
// B=16, N=512, D=1024, H=16, hd=64. scale = D^-0.5 = 1/32.
//
// R9 -> R10:
//  - PROLOGUE FUSION: cast_bf16 + cast4_bf16 + bias_perm merged into one
//    kernel (7168 blocks, branch on blockIdx). 6 launches -> 4: removes two
//    inter-node drains/ramps on small kernels (the dispatch sum is ~190us vs
//    ~255 measured -> the gap is tail/launch overhead, not the hot kernels).
//  - attn QK^T SWAPPED (mfma(K,Q)): C holds P[j][q] with q lane-local (l16).
//    sP layout [q][j] and the PV read side are byte-identical to R9, but the
//    write side becomes 4x ds_write_b64 per j-tile instead of 16 scalar
//    ds_write_b16; lsum 4 regs -> 1; final reduce 2 shfl_xor + 4 shfl instead
//    of 16 shuffles. bias_perm gains an in-LDS 64x64 transpose so Bp chunks
//    arrive in the new per-lane order (coalesced f32 loads preserved).
//  - qkv/oproj byte-identical to R9 (qkv at structural ceiling ~70us,
//    FETCH/WRITE at ideal 49.2MB, 0 bank conflicts).

typedef unsigned short u16;
typedef unsigned int   u32;
typedef __attribute__((ext_vector_type(8))) short bf8;   // 8 x bf16 (4 VGPRs)
typedef __attribute__((ext_vector_type(4))) float f4;    // 4 x f32 accum

#define LOG2E 1.4426950408889634f

__device__ __forceinline__ u16 f2bf(float x) {
  u32 u = __float_as_uint(x);
  u += 0x7FFF + ((u >> 16) & 1);        // round-to-nearest-even
  return (u16)(u >> 16);
}

__device__ __forceinline__ float bf2f(u16 x) {
  return __uint_as_float(((u32)x) << 16);
}

// async global->LDS, 16B per lane. LDS dest = wave-uniform base + lane*16.
__device__ __forceinline__ void gl2lds16(const void* g, void* l) {
  __builtin_amdgcn_global_load_lds(
      (const __attribute__((address_space(1))) u32*)g,
      (__attribute__((address_space(3))) u32*)l, 16, 0, 0);
}

// ---------------- fused prologue ----------------
// blocks [0,4096): cast x -> bf16          (1M uint4 = 8M bf16)
// blocks [4096,6144): cast Wq/Wk/Wv/Wo     (512K uint4)
// blocks [6144,7168): bias = bf16((sp+ed)*log2e), permuted + transposed so
//   attn lane tid of (b,qt,jt) reads its 16 values as one 32B chunk with
//   element order idx=nb*4+r <-> bias[q=(wave<<4)+l16][j=(nb<<4)+(quad<<2)+r].

__global__ __launch_bounds__(256) void prologue(
    const float* __restrict__ x,
    const float* __restrict__ sp, const float* __restrict__ ed,
    const float* __restrict__ s0, const float* __restrict__ s1,
    const float* __restrict__ s2, const float* __restrict__ s3,
    uint4* __restrict__ xb,
    uint4* __restrict__ d0, uint4* __restrict__ d1,
    uint4* __restrict__ d2, uint4* __restrict__ d3,
    u16* __restrict__ Bp) {
  __shared__ u16 t[64][65];              // bias transpose tile (+1 pad)
  const int bid = blockIdx.x, tid = threadIdx.x;

  if (bid < 6144) {
    const int i = (bid < 4096) ? (bid << 8) + tid : ((bid - 4096) << 8) + tid;
    const float* src;
    uint4* dst;
    int j;
    if (bid < 4096) {
      src = x; dst = xb; j = i;
    } else {
      const int w = i >> 17;
      j = i & 131071;
      src = (w == 0) ? s0 : (w == 1) ? s1 : (w == 2) ? s2 : s3;
      dst = (w == 0) ? d0 : (w == 1) ? d1 : (w == 2) ? d2 : d3;
    }
    const float4* s = (const float4*)src;
    const float4 a = s[2 * j], c = s[2 * j + 1];
    uint4 o;
    o.x = (u32)f2bf(a.x) | ((u32)f2bf(a.y) << 16);
    o.y = (u32)f2bf(a.z) | ((u32)f2bf(a.w) << 16);
    o.z = (u32)f2bf(c.x) | ((u32)f2bf(c.y) << 16);
    o.w = (u32)f2bf(c.z) | ((u32)f2bf(c.w) << 16);
    dst[j] = o;
    return;
  }

  // bias branch
  const int r3 = bid - 6144;             // 0..1023
  const int jt = r3 & 7, qt = (r3 >> 3) & 7, b = r3 >> 6;
  const int wave = tid >> 6, quad = (tid >> 4) & 3, l16 = tid & 15;
  const int qrl = (wave << 4) + (quad << 2);

  // phase 1: coalesced f32 loads (l16 -> contiguous cols), bf16 to LDS
#pragma unroll
  for (int nb = 0; nb < 4; nb++) {
    const int col = (nb << 4) + l16;
#pragma unroll
    for (int r = 0; r < 4; r++) {
      const int row = qrl + r;
      const size_t idx = ((size_t)b << 18) +
                         (size_t)((qt << 6) + row) * 512 + (jt << 6) + col;
      t[row][col] = f2bf((sp[idx] + ed[idx]) * LOG2E);
    }
  }
  __syncthreads();

  // phase 2: gather the swapped-QKT order, write 32B chunk
  union { u16 a[16]; uint4 v[2]; } tmp;
#pragma unroll
  for (int nb = 0; nb < 4; nb++)
#pragma unroll
    for (int r = 0; r < 4; r++)
      tmp.a[nb * 4 + r] = t[(wave << 4) + l16][(nb << 4) + (quad << 2) + r];
  uint4* out = (uint4*)Bp + ((((size_t)b * 8 + qt) * 8 + jt) * 256 + tid) * 2;
  out[0] = tmp.v[0];
  out[1] = tmp.v[1];
}

// ---------------- GEMM core: C(128x128) = A(128x1024) * Bt(128x1024)^T ----------------
// A row-major [M][1024], Bt row-major [Nout][1024] (computes A @ Bt^T).
// LDS tiles are [128 rows][8 chunks of 16B], slot (r,c) holds global chunk c^(r&7).
// SWAP=true computes C^T fragments (mfma(B,A)): lane&15 -> M dim, (quad,reg) -> N
// dim, so the 4 regs of each fragment are CONSECUTIVE along N -> packed stores.

template <bool SWAP>
__device__ __forceinline__ void gemm_core(const u16* __restrict__ A,
                                          const u16* __restrict__ Bt,
                                          int m0, int n0,
                                          u16* lA, u16* lB, f4 acc[4][4]) {
  const int tid  = threadIdx.x;
  const int wave = tid >> 6;
  const int lane = tid & 63;
  const int quad = lane >> 4;
  const int l16  = lane & 15;
  const int wm   = (wave >> 1) << 6;
  const int wn   = (wave & 1) << 6;
  const int srow = tid >> 3;
  const int scol = ((tid & 7) ^ (srow & 7)) << 3;   // swizzled source chunk
  const int c0   = (quad ^ (l16 & 7)) << 3;         // swizzled read offset, kk=0

  f4 zero = {0.f, 0.f, 0.f, 0.f};
#pragma unroll
  for (int mi = 0; mi < 4; mi++)
#pragma unroll
    for (int ni = 0; ni < 4; ni++) acc[mi][ni] = zero;

  const u16* Ab = A  + (size_t)(m0 + srow) * 1024 + scol;
  const u16* Bb = Bt + (size_t)(n0 + srow) * 1024 + scol;

  for (int k0 = 0; k0 < 1024; k0 += 64) {
    __syncthreads();   // protect LDS from previous iteration's readers
#pragma unroll
    for (int i = 0; i < 4; i++) {
      gl2lds16(Ab + (size_t)(i << 5) * 1024 + k0,
               (char*)lA + (((i << 8) + (wave << 6)) << 4));
      gl2lds16(Bb + (size_t)(i << 5) * 1024 + k0,
               (char*)lB + (((i << 8) + (wave << 6)) << 4));
    }
    __syncthreads();   // drains vmcnt(0) -> tiles visible
#pragma unroll
    for (int kk = 0; kk < 64; kk += 32) {
      const int o = c0 ^ kk;
      bf8 af[4], bfr[4];
#pragma unroll
      for (int mi = 0; mi < 4; mi++)
        af[mi] = *(const bf8*)(lA + (wm + (mi << 4) + l16) * 64 + o);
#pragma unroll
      for (int ni = 0; ni < 4; ni++)
        bfr[ni] = *(const bf8*)(lB + (wn + (ni << 4) + l16) * 64 + o);
#pragma unroll
      for (int mi = 0; mi < 4; mi++)
#pragma unroll
        for (int ni = 0; ni < 4; ni++) {
          if (SWAP)
            acc[mi][ni] = __builtin_amdgcn_mfma_f32_16x16x32_bf16(
                bfr[ni], af[mi], acc[mi][ni], 0, 0, 0);
          else
            acc[mi][ni] = __builtin_amdgcn_mfma_f32_16x16x32_bf16(
                af[mi], bfr[ni], acc[mi][ni], 0, 0, 0);
        }
    }
  }
}

// ---------------- QKV projection ----------------
// XCD remap: flat bits [2:0]=m_lo [5:3]=n_tile [8:6]=m_hi [10:9]=proj.
// Q is pre-scaled by log2e/32 (softmax scale folded in; Q feeds only attn).

__global__ __launch_bounds__(256) void qkv_kernel(
    const u16* __restrict__ xb, const u16* __restrict__ wq,
    const u16* __restrict__ wk, const u16* __restrict__ wv,
    u16* __restrict__ Qh, u16* __restrict__ Kh, u16* __restrict__ Vt) {
  __shared__ __align__(16) u16 lA[128 * 64];
  __shared__ __align__(16) u16 lB[128 * 64];
  const int flat = blockIdx.x + (blockIdx.y << 3) + (blockIdx.z << 9);
  const int m_tile = (flat & 7) | (((flat >> 6) & 7) << 3);
  const int n_tile = (flat >> 3) & 7;
  const int proj = flat >> 9;
  const int m0 = m_tile << 7, n0 = n_tile << 7;
  const u16* W = (proj == 0) ? wq : (proj == 1) ? wk : wv;

  const int tid = threadIdx.x, wave = tid >> 6, lane = tid & 63;
  const int quad = lane >> 4, l16 = lane & 15;
  const int wm = (wave >> 1) << 6, wn = (wave & 1) << 6;
  f4 acc[4][4];

  if (proj == 2) {
    // V: normal orientation; C rows (quad,reg) = tokens, which are the
    // contiguous dim of Vt [B,H,hd,512] -> ushort4 over 4 consecutive n.
    gemm_core<false>(xb, W, m0, n0, lA, lB, acc);
#pragma unroll
    for (int mi = 0; mi < 4; mi++) {
      const int gmb = m0 + wm + (mi << 4) + (quad << 2);
      const int b = gmb >> 9, nb = gmb & 511;
#pragma unroll
      for (int ni = 0; ni < 4; ni++) {
        const int gn = n0 + wn + (ni << 4) + l16;
        const int h = gn >> 6, hdi = gn & 63;
        ushort4 pk;
        pk.x = f2bf(acc[mi][ni][0]);
        pk.y = f2bf(acc[mi][ni][1]);
        pk.z = f2bf(acc[mi][ni][2]);
        pk.w = f2bf(acc[mi][ni][3]);
        *(ushort4*)(Vt + ((size_t)((b << 4) + h) * 64 + hdi) * 512 + nb) = pk;
      }
    }
  } else {
    // Q/K: transposed fragments; (quad,reg) = hd (contiguous in Qh/Kh),
    // lane&15 = token row -> one ushort4 per fragment.
    gemm_core<true>(xb, W, m0, n0, lA, lB, acc);
    u16* dst = (proj == 0) ? Qh : Kh;
    const float qs = (proj == 0) ? (LOG2E / 32.0f) : 1.0f;
#pragma unroll
    for (int mi = 0; mi < 4; mi++) {
      const int gm = m0 + wm + (mi << 4) + l16;      // token row
      const int b = gm >> 9, n = gm & 511;
#pragma unroll
      for (int ni = 0; ni < 4; ni++) {
        const int gn = n0 + wn + (ni << 4) + (quad << 2);  // hd dim
        const int h = gn >> 6, hdi = gn & 63;
        ushort4 pk;
        pk.x = f2bf(acc[mi][ni][0] * qs);
        pk.y = f2bf(acc[mi][ni][1] * qs);
        pk.z = f2bf(acc[mi][ni][2] * qs);
        pk.w = f2bf(acc[mi][ni][3] * qs);
        *(ushort4*)(dst + ((size_t)((b << 4) + h) * 512 + n) * 64 + hdi) = pk;
      }
    }
  }
}

// ---------------- output projection ----------------
// XCD remap: flat bits [2:0]=m_lo [5:3]=n_tile [8:6]=m_hi.
// Transposed fragments -> float4 stores (gn contiguous).

__global__ __launch_bounds__(256) void oproj_kernel(const u16* __restrict__ Ob,
                                                    const u16* __restrict__ wo,
                                                    float* __restrict__ out) {
  __shared__ __align__(16) u16 lA[128 * 64];
  __shared__ __align__(16) u16 lB[128 * 64];
  const int flat = blockIdx.x + (blockIdx.y << 3);
  const int m0 = ((flat & 7) | (((flat >> 6) & 7) << 3)) << 7;
  const int n0 = ((flat >> 3) & 7) << 7;
  f4 acc[4][4];
  gemm_core<true>(Ob, wo, m0, n0, lA, lB, acc);

  const int tid = threadIdx.x, wave = tid >> 6, lane = tid & 63;
  const int quad = lane >> 4, l16 = lane & 15;
  const int wm = (wave >> 1) << 6, wn = (wave & 1) << 6;
#pragma unroll
  for (int mi = 0; mi < 4; mi++) {
    const int gm = m0 + wm + (mi << 4) + l16;
#pragma unroll
    for (int ni = 0; ni < 4; ni++) {
      const int gn = n0 + wn + (ni << 4) + (quad << 2);
      float4 f;
      f.x = acc[mi][ni][0];
      f.y = acc[mi][ni][1];
      f.z = acc[mi][ni][2];
      f.w = acc[mi][ni][3];
      *(float4*)(out + (size_t)gm * 1024 + gn) = f;
    }
  }
}

// ---------------- fused attention: one wg per (64 q-rows, h, b) ----------------
// Q,K: [B,H,512,64] bf16 (Q pre-scaled by log2e/32).  Vt: [B,H,64,512] bf16.
// Stage-drain skeleton (proven): per j-tile { bias loads; sync; stage K,V
// (4 gl2lds); sync; QK^T(SWAPPED)+softmax->sP; PV }.
// Swapped QK^T: s = mfma(K,Q) -> C holds P[j=(nb<<4)+(quad<<2)+r][q=l16]:
// q is LANE-LOCAL. sP stays [q][j] (stride-72) and the PV read side is
// identical to R9, but writes are 4x ds_write_b64/j-tile (was 16 scalar b16),
// lsum is one register, and the row-sum reduce is 2 shfl_xor.
// Q fragments direct global->reg; LDS 25600 B; launch_bounds(256,5).

__global__ __launch_bounds__(256, 5) void attn_kernel(
    const u16* __restrict__ Qh, const u16* __restrict__ Kh,
    const u16* __restrict__ Vt, const u16* __restrict__ Bp,
    u16* __restrict__ Ob) {
  __shared__ __align__(16) u16 sK[64 * 64];
  __shared__ __align__(16) u16 sV[64 * 64];        // [hd][j] layout
  __shared__ __align__(16) u16 sP[4 * 16 * 72];    // per-wave [16 q][64 j], stride 72
  const int flat = blockIdx.x + (blockIdx.y << 3) + (blockIdx.z << 7);
  const int qt = (flat >> 3) & 7;
  const int h  = (flat >> 6) & 15;
  const int b  = (flat & 7) | (((flat >> 10) & 1) << 3);
  const int q0 = qt << 6;
  const int tid = threadIdx.x, wave = tid >> 6, lane = tid & 63;
  const int quad = lane >> 4, l16 = lane & 15;
  const int c0  = (quad ^ (l16 & 7)) << 3;                 // swizzled read offset
  const int swb = (((tid & 7) ^ ((tid >> 3) & 7)) << 4);   // swizzled staging byte off

  const u16* Qg = Qh + ((size_t)((b << 4) + h) * 512 + q0) * 64;
  const u16* Kg = Kh + (size_t)((b << 4) + h) * 512 * 64;
  const u16* Vg = Vt + (size_t)((b << 4) + h) * 64 * 512;
  const uint4* Bpg = (const uint4*)Bp + (((size_t)b * 8 + qt) * 8 * 256 + tid) * 2;

  // Q fragments direct from global (contiguous 16B chunks, L2-hot)
  const bf8 aq0 = *(const bf8*)(Qg + ((wave << 4) + l16) * 64 + (quad << 3));
  const bf8 aq1 = *(const bf8*)(Qg + ((wave << 4) + l16) * 64 + 32 + (quad << 3));

  f4 o[4];
  f4 zero = {0.f, 0.f, 0.f, 0.f};
#pragma unroll
  for (int i = 0; i < 4; i++) o[i] = zero;
  float lsum = 0.f;                       // row sum for q = l16 (partial over quads)
  const int qrl = (wave << 4) + (quad << 2);

  for (int j0 = 0; j0 < 512; j0 += 64) {
    // bias chunk for this j-tile: 32B/lane, issued before the drain barrier
    const uint4 bc0 = Bpg[(j0 >> 6) * 512];
    const uint4 bc1 = Bpg[(j0 >> 6) * 512 + 1];
    const u32 bw[8] = {bc0.x, bc0.y, bc0.z, bc0.w, bc1.x, bc1.y, bc1.z, bc1.w};

    __syncthreads();   // protect LDS from previous iteration's readers
#pragma unroll
    for (int i = 0; i < 2; i++) {
      const int e = (i << 8) + tid;
      gl2lds16((const char*)Kg + (size_t)j0 * 128 + (e >> 3) * 128 + swb,
               (char*)sK + (((i << 8) + (wave << 6)) << 4));
      gl2lds16((const char*)Vg + (size_t)(e >> 3) * 1024 + j0 * 2 + swb,
               (char*)sV + (((i << 8) + (wave << 6)) << 4));
    }
    __syncthreads();   // drains vmcnt(0) -> K/V tiles visible

    u16* pw = sP + wave * (16 * 72);
#pragma unroll
    for (int nb = 0; nb < 4; nb++) {
      bf8 b0 = *(const bf8*)(sK + ((nb << 4) + l16) * 64 + c0);
      bf8 b1 = *(const bf8*)(sK + ((nb << 4) + l16) * 64 + (c0 ^ 32));
      f4 s = zero;
      // SWAPPED: A=K (m=j), B=Q (n=q) -> C[row=(quad,r)=j][col=l16=q]
      s = __builtin_amdgcn_mfma_f32_16x16x32_bf16(b0, aq0, s, 0, 0, 0);
      s = __builtin_amdgcn_mfma_f32_16x16x32_bf16(b1, aq1, s, 0, 0, 0);
      union { u16 a[4]; uint2 v; } pp;
#pragma unroll
      for (int r = 0; r < 4; r++) {
        const u32 w = bw[nb * 2 + (r >> 1)];
        const float bias = bf2f((r & 1) ? (u16)(w >> 16) : (u16)(w & 0xFFFF));
        const float ev = exp2f(s[r] + bias);   // scale+log2e pre-folded
        lsum += ev;
        pp.a[r] = f2bf(ev);
      }
      // P[q=l16][j=nb*16+quad*4 .. +3] -> one 8B write (8B-aligned: stride 144B)
      *(uint2*)(pw + l16 * 72 + (nb << 4) + (quad << 2)) = pp.v;
    }

    // P fragments for PV: A[m=q=l16][k=j] -> identical read path to R9
    bf8 ap0 = *(const bf8*)(pw + l16 * 72 + (quad << 3));
    bf8 ap1 = *(const bf8*)(pw + l16 * 72 + 32 + (quad << 3));
#pragma unroll
    for (int db = 0; db < 4; db++) {
      bf8 v0 = *(const bf8*)(sV + ((db << 4) + l16) * 64 + c0);
      bf8 v1 = *(const bf8*)(sV + ((db << 4) + l16) * 64 + (c0 ^ 32));
      o[db] = __builtin_amdgcn_mfma_f32_16x16x32_bf16(ap0, v0, o[db], 0, 0, 0);
      o[db] = __builtin_amdgcn_mfma_f32_16x16x32_bf16(ap1, v1, o[db], 0, 0, 0);
    }
  }

  // epilogue: complete the row sums (sum over the 4 quad copies of each q=l16),
  // redistribute 1/sum to the (quad,r)-indexed output rows, store.
  float s = lsum;
  s += __shfl_xor(s, 16);
  s += __shfl_xor(s, 32);
  const float inv_all = 1.f / s;          // valid for q = l16 on every lane
#pragma unroll
  for (int r = 0; r < 4; r++) {
    const float inv = __shfl(inv_all, (quad << 2) + r);   // lane with l16 = q_local
    const int gr = q0 + qrl + r;
#pragma unroll
    for (int db = 0; db < 4; db++)
      Ob[(size_t)((b << 9) + gr) * 1024 + (h << 6) + (db << 4) + l16] =
          f2bf(o[db][r] * inv);
  }
}

// ---------------- launch ----------------

extern "C" void kernel_launch(void* const* d_in, const int* in_sizes, int n_in,
                              void* d_out, int out_size, void* d_ws, size_t ws_size,
                              hipStream_t stream) {
  const float* x  = (const float*)d_in[0];
  const float* sp = (const float*)d_in[1];
  const float* ed = (const float*)d_in[2];
  const float* Wq = (const float*)d_in[3];
  const float* Wk = (const float*)d_in[4];
  const float* Wv = (const float*)d_in[5];
  const float* Wo = (const float*)d_in[6];
  float* out = (float*)d_out;

  char* w = (char*)d_ws;
  u16* xb  = (u16*)(w);                  // 16 MB  : x bf16 [8192][1024]
  u16* wqb = (u16*)(w + 16777216);       // 2 MB
  u16* wkb = (u16*)(w + 18874368);
  u16* wvb = (u16*)(w + 20971520);
  u16* wob = (u16*)(w + 23068672);
  u16* Qh  = (u16*)(w + 25165824);       // 16 MB  : [B,H,512,64] (pre-scaled)
  u16* Kh  = (u16*)(w + 41943040);       // 16 MB
  u16* Vt  = (u16*)(w + 58720256);       // 16 MB  : [B,H,64,512]
  u16* Ob  = (u16*)(w + 75497472);       // 16 MB  : [8192][1024]
  u16* Bp  = (u16*)(w + 92274688);       // 8 MB   : permuted bf16((sp+ed)*log2e)

  prologue<<<7168, 256, 0, stream>>>(x, sp, ed, Wq, Wk, Wv, Wo,
                                     (uint4*)xb, (uint4*)wqb, (uint4*)wkb,
                                     (uint4*)wvb, (uint4*)wob, Bp);

  qkv_kernel<<<dim3(8, 64, 3), 256, 0, stream>>>(xb, wqb, wkb, wvb, Qh, Kh, Vt);
  attn_kernel<<<dim3(8, 16, 16), 256, 0, stream>>>(Qh, Kh, Vt, Bp, Ob);
  oproj_kernel<<<dim3(8, 64, 1), 256, 0, stream>>>(Ob, wob, out);
}